// Round 3
// baseline (551.813 us; speedup 1.0000x reference)
//
#include <hip/hip_runtime.h>
#include <cmath>

#define BB 2
#define KK 12
#define HH 120
#define WW 160
#define HW (HH*WW)
#define DD 128
#define NB 100
#define DMAXF 6.0f
#define NLINES (BB*DD*DD)
#define NVOX (BB*DD*DD*DD)
#define SDP 161   // padded LDS row stride: 161%32==1 -> conflict-free column reads
#define SLAB 32

// ---------------- K1: per-pixel softmax/argmax/depth-index ----------------
__global__ void k1_pixel(const float* __restrict__ sem2d, const float* __restrict__ depth,
                         float* __restrict__ feats_sm, float* __restrict__ stuffflag,
                         int* __restrict__ di_arr) {
    int t = blockIdx.x * blockDim.x + threadIdx.x;
    if (t >= BB * HW) return;
    int b = t / HW, p = t - b * HW;
    const float* sp = sem2d + (size_t)b * KK * HW + p;
    float v[KK];
    float mx = -INFINITY; int am = 0;
#pragma unroll
    for (int k = 0; k < KK; k++) {
        v[k] = sp[(size_t)k * HW];
        if (v[k] > mx) { mx = v[k]; am = k; }
    }
    float s = 0.f;
#pragma unroll
    for (int k = 0; k < KK; k++) { v[k] = expf(v[k] - mx); s += v[k]; }
    float inv = 1.f / s;
    float* fp = feats_sm + (size_t)b * KK * HW + p;
#pragma unroll
    for (int k = 0; k < KK; k++) fp[(size_t)k * HW] = v[k] * inv;
    stuffflag[t] = (am >= 10) ? 1.f : 0.f;
    float d = fminf(depth[t], DMAXF);
    di_arr[t] = (int)((d / DMAXF) * 100.0f);   // exact op order: div then mul
}

// ---------------- K23: fused erosion + border fill + find_none + dmb (one block per batch) ----
__global__ __launch_bounds__(256) void k23_stuff(const float* __restrict__ stuffflag,
                                                 const float* __restrict__ depth,
                                                 int* __restrict__ dmb_arr) {
    __shared__ float sd[HH * SDP];          // 77.3 KB
    __shared__ unsigned int bA[600];        // packed stuff bits (5 words/row)
    __shared__ unsigned int bB[600];        // horizontally eroded bits
    __shared__ float ymax[HH], xmax[WW], colmax[WW], rowmax[HH];
    __shared__ float sufc[WW], sufr[HH];
    __shared__ float sxv[WW], syv[HH];
    __shared__ float vv[4];
    int b = blockIdx.x, t = threadIdx.x;
    const float* sf = stuffflag + b * HW;
    const float* dp = depth + b * HW;

    for (int it = 0; it < HW / 256; ++it) {
        int p = it * 256 + t;
        bool fl = sf[p] > 0.5f;
        unsigned long long m = __ballot(fl);
        int lane = t & 63;
        if (lane == 0)  bA[p >> 5] = (unsigned int)m;
        if (lane == 32) bA[p >> 5] = (unsigned int)(m >> 32);
    }
    __syncthreads();

    // horizontal 5-tap erosion, OOB = 1 (minpool pads with +inf)
    for (int q = t; q < 600; q += 256) {
        int w = q % 5;
        unsigned int cur = bA[q];
        unsigned int left  = (w > 0) ? bA[q - 1] : 0xFFFFFFFFu;
        unsigned int right = (w < 4) ? bA[q + 1] : 0xFFFFFFFFu;
        unsigned int sL1 = (cur >> 1) | (right << 31);
        unsigned int sL2 = (cur >> 2) | (right << 30);
        unsigned int sR1 = (cur << 1) | (left >> 31);
        unsigned int sR2 = (cur << 2) | (left >> 30);
        bB[q] = cur & sL1 & sL2 & sR1 & sR2;
    }
    __syncthreads();

    // vertical 5-tap erosion (OOB rows = 1)
    for (int q = t; q < 600; q += 256) {
        int h = q / 5, w = q - h * 5;
        unsigned int v = 0xFFFFFFFFu;
#pragma unroll
        for (int dh = -2; dh <= 2; ++dh) {
            int hh = h + dh;
            if (hh >= 0 && hh < HH) v &= bB[hh * 5 + w];
        }
        bA[q] = v;
    }
    __syncthreads();

    for (int it = 0; it < HW / 256; ++it) {
        int p = it * 256 + t;
        int h = p / WW, w = p - h * WW;
        unsigned int bit = (bA[p >> 5] >> (p & 31)) & 1u;
        float d = fminf(dp[p], DMAXF);
        sd[h * SDP + w] = bit ? d : 0.f;
    }
    __syncthreads();

    if (t < HH) { float m = -INFINITY; for (int w = 0; w < WW; w++) m = fmaxf(m, sd[t * SDP + w]); ymax[t] = m; }
    if (t < WW) { float m = -INFINITY; for (int h = 0; h < HH; h++) m = fmaxf(m, sd[h * SDP + t]); xmax[t] = m; }
    __syncthreads();

    if (t == 0) {
        float f = 0.f, l = 0.f;
        for (int h = 0; h < HH; h++) { if (ymax[h] != 0.f) { f = ymax[h]; break; } }
        for (int h = HH - 1; h >= 0; h--) { if (ymax[h] != 0.f) { l = ymax[h]; break; } }
        vv[0] = f; vv[1] = l;
    }
    if (t == 1) {
        float f = 0.f, l = 0.f;
        for (int w = 0; w < WW; w++) { if (xmax[w] != 0.f) { f = xmax[w]; break; } }
        for (int w = WW - 1; w >= 0; w--) { if (xmax[w] != 0.f) { l = xmax[w]; break; } }
        vv[2] = f; vv[3] = l;
    }
    __syncthreads();
    float v1 = vv[0], v2 = vv[1], v3 = vv[2], v4 = vv[3];

    auto sdval = [&](int h, int w) -> float {
        float x = sd[h * SDP + w];
        if (w == 0)      return (x == 0.f) ? v3 : x;
        if (w == WW - 1) return (x == 0.f) ? v4 : x;
        if (h == 0)      return (x == 0.f) ? v1 : x;
        if (h == HH - 1) return (x == 0.f) ? v2 : x;
        return x;
    };
    if (t < WW) { float m = -INFINITY; for (int h = 0; h < HH; h++) m = fmaxf(m, sdval(h, t)); colmax[t] = m; }
    if (t < HH) { float m = -INFINITY; for (int w = 0; w < WW; w++) m = fmaxf(m, sdval(t, w)); rowmax[t] = m; }
    __syncthreads();

    if (t == 0) {
        float m = INFINITY;
        for (int i = WW - 1; i >= 0; i--) { sufc[i] = m; float a = colmax[i]; if (a != 0.f) m = fminf(m, a); }
        m = INFINITY;
        for (int i = 0; i < WW; i++) {
            float a = colmax[i];
            float l = (m == INFINITY) ? 0.f : m;
            float r = (sufc[i] == INFINITY) ? 0.f : sufc[i];
            float val = (a == 0.f) ? fmaxf(l, r) : a;
            if (val != 0.f) m = fminf(m, val);
            sxv[i] = val;
        }
    }
    if (t == 1) {
        float m = INFINITY;
        for (int i = HH - 1; i >= 0; i--) { sufr[i] = m; float a = rowmax[i]; if (a != 0.f) m = fminf(m, a); }
        m = INFINITY;
        for (int i = 0; i < HH; i++) {
            float a = rowmax[i];
            float l = (m == INFINITY) ? 0.f : m;
            float r = (sufr[i] == INFINITY) ? 0.f : sufr[i];
            float val = (a == 0.f) ? fmaxf(l, r) : a;
            if (val != 0.f) m = fminf(m, val);
            syv[i] = val;
        }
    }
    __syncthreads();

    for (int it = 0; it < HW / 256; ++it) {
        int p = it * 256 + t;
        int h = p / WW, w = p - h * WW;
        float dm = fminf(sxv[w], syv[h]);
        dmb_arr[b * HW + p] = (int)((dm / DMAXF) * 100.0f);
    }
}

// ---------------- K45: fused features writer + voxel gather ----------------
__device__ inline void comp1(float o, int di, int db, int bin, float& dw, float& sg, float& ad) {
    bool dwk = (bin > di - 3) && (bin < db + 5);
    float s = 1.f / (1.f + __expf(-o));
    dw = dwk ? s : 0.f;
    float df = ((float)(bin - di)) / 100.0f * DMAXF;
    sg = (float)((bin > di) - (bin < di));
    ad = fabsf(df);
}

#define FEAT_BLOCKS (BB * NB * (HW/4) / 256)   // 3750

__global__ void k45_feat_gather(const float4* __restrict__ occ4, const float4* __restrict__ fs4,
                                const int4* __restrict__ di4, const int4* __restrict__ dmb4,
                                float4* __restrict__ out4,
                                const int* __restrict__ kept, const float4* __restrict__ mapping,
                                const int* __restrict__ di_arr, const int* __restrict__ dmb_arr,
                                float* __restrict__ out_fk, unsigned int* __restrict__ fk_pk,
                                unsigned int* __restrict__ kept_pk, int* __restrict__ counters) {
    if (blockIdx.x < FEAT_BLOCKS) {
        const int HW4 = HW / 4;
        int t = blockIdx.x * blockDim.x + threadIdx.x;   // exactly B*NB*HW4 threads
        int b = t / (NB * HW4);
        int r = t - b * (NB * HW4);
        int bin = r / HW4;
        int p4 = r - bin * HW4;
        int4 di = di4[b * HW4 + p4];
        int4 db = dmb4[b * HW4 + p4];
        float4 o = occ4[t];
        float4 dw, sgn, adf;
        comp1(o.x, di.x, db.x, bin, dw.x, sgn.x, adf.x);
        comp1(o.y, di.y, db.y, bin, dw.y, sgn.y, adf.y);
        comp1(o.z, di.z, db.z, bin, dw.z, sgn.z, adf.z);
        comp1(o.w, di.w, db.w, bin, dw.w, sgn.w, adf.w);
        size_t base = (size_t)(b * 15 * NB + bin) * HW4 + p4;
        const float4* fp = fs4 + (size_t)b * KK * HW4 + p4;
#pragma unroll
        for (int c = 0; c < KK; c++) out4[base + (size_t)c * NB * HW4] = fp[(size_t)c * HW4];
        out4[base + (size_t)12 * NB * HW4] = dw;
        out4[base + (size_t)13 * NB * HW4] = sgn;
        out4[base + (size_t)14 * NB * HW4] = adf;
    } else {
        int v = (blockIdx.x - FEAT_BLOCKS) * blockDim.x + threadIdx.x;  // exactly NVOX threads
        if (v == 0) { counters[0] = 0; counters[1] = 0; }   // zero-init for kA (stream-ordered)
        float4 m = mapping[v];
        int bi = (int)m.x, xi = (int)m.y, yi = (int)m.z;
        int dIdx = (int)((m.w * 100.0f) / DMAXF);   // exact op order: mul then div
        int kp = kept[v];
        int pp = bi * HW + yi * WW + xi;
        int di = di_arr[pp], db = dmb_arr[pp];
        bool dwk = (dIdx > di - 3) && (dIdx < db + 5);
        bool fk = (kp != 0) && dwk;
        out_fk[v] = fk ? 1.f : 0.f;
        unsigned long long mb = __ballot(fk);
        unsigned long long mk = __ballot(kp != 0);
        int lane = threadIdx.x & 63;
        if (lane == 0)  { fk_pk[v >> 5] = (unsigned int)mb;         kept_pk[v >> 5] = (unsigned int)mk; }
        if (lane == 32) { fk_pk[v >> 5] = (unsigned int)(mb >> 32); kept_pk[v >> 5] = (unsigned int)(mk >> 32); }
    }
}

// ---------------- bitwise 128-bit k-dilation ----------------
__device__ inline void kdil128(unsigned int w0, unsigned int w1, unsigned int w2, unsigned int w3,
                               unsigned int* r) {
    unsigned int a0 = w0, a1 = w1, a2 = w2, a3 = w3;
    a0 |= w0 << 1; a1 |= (w1 << 1) | (w0 >> 31); a2 |= (w2 << 1) | (w1 >> 31); a3 |= (w3 << 1) | (w2 >> 31);
    a0 |= w0 << 2; a1 |= (w1 << 2) | (w0 >> 30); a2 |= (w2 << 2) | (w1 >> 30); a3 |= (w3 << 2) | (w2 >> 30);
    a0 |= (w0 >> 1) | (w1 << 31); a1 |= (w1 >> 1) | (w2 << 31); a2 |= (w2 >> 1) | (w3 << 31); a3 |= w3 >> 1;
    a0 |= (w0 >> 2) | (w1 << 30); a1 |= (w1 >> 2) | (w2 << 30); a2 |= (w2 >> 2) | (w3 << 30); a3 |= w3 >> 2;
    r[0] = a0; r[1] = a1; r[2] = a2; r[3] = a3;
}

// ---------------- KA: slab-fused maxpool3d(fk) & kept -> pad0, + any-flag ----------------
// grid: BB * (DD/SLAB) = 8 blocks x 512 threads; LDS = 2 x 36x128x16B = 147.5 KB
__global__ __launch_bounds__(512) void kA_pad(const uint4* __restrict__ fk_pk,
                                              const uint4* __restrict__ kept_pk,
                                              uint4* __restrict__ pad0, int* __restrict__ counters) {
    __shared__ uint4 fkS[SLAB + 4][DD];
    __shared__ uint4 jkS[SLAB + 4][DD];
    int b = blockIdx.x / (DD / SLAB);
    int i0 = (blockIdx.x % (DD / SLAB)) * SLAB;
    int t = threadIdx.x;

    for (int q = t; q < (SLAB + 4) * DD; q += 512) {
        int r = q >> 7, j = q & 127;
        int gi = i0 - 2 + r;
        uint4 v = make_uint4(0, 0, 0, 0);
        if (gi >= 0 && gi < DD) v = fk_pk[(b * DD + gi) * DD + j];
        fkS[r][j] = v;
    }
    __syncthreads();

    for (int q = t; q < (SLAB + 4) * DD; q += 512) {
        int r = q >> 7, j = q & 127;
        unsigned int a0 = 0, a1 = 0, a2 = 0, a3 = 0;
#pragma unroll
        for (int dj = -2; dj <= 2; dj++) {
            int jj = j + dj; if (jj < 0 || jj >= DD) continue;
            uint4 x = fkS[r][jj];
            a0 |= x.x; a1 |= x.y; a2 |= x.z; a3 |= x.w;
        }
        unsigned int rr[4]; kdil128(a0, a1, a2, a3, rr);
        jkS[r][j] = make_uint4(rr[0], rr[1], rr[2], rr[3]);
    }
    __syncthreads();

    unsigned int any = 0;
    for (int q = t; q < SLAB * DD; q += 512) {
        int r = (q >> 7) + 2, j = q & 127;
        int gi = i0 + (q >> 7);
        unsigned int a0 = 0, a1 = 0, a2 = 0, a3 = 0;
#pragma unroll
        for (int di = -2; di <= 2; di++) {
            uint4 x = jkS[r + di][j];
            a0 |= x.x; a1 |= x.y; a2 |= x.z; a3 |= x.w;
        }
        uint4 kk = kept_pk[(b * DD + gi) * DD + j];
        a0 &= kk.x; a1 &= kk.y; a2 &= kk.z; a3 &= kk.w;
        pad0[(b * DD + gi) * DD + j] = make_uint4(a0, a1, a2, a3);
        any |= a0 | a1 | a2 | a3;
    }
    unsigned long long bal = __ballot(any != 0);
    if ((t & 63) == 0 && bal) atomicOr(&counters[b], 1);
}

// ---------------- KB: slab-fused union(+special,&~fk) -> maxpool3d -> float unpack ----------------
// grid: 8 blocks x 512 threads; LDS = 2 x 37x128x16B = 151.6 KB
__global__ __launch_bounds__(512) void kB_mask(const uint4* __restrict__ pad0,
                                               const uint4* __restrict__ fk_pk,
                                               const int* __restrict__ counters,
                                               float4* __restrict__ outm) {
    __shared__ uint4 padS[SLAB + 5][DD];
    __shared__ uint4 fkS[SLAB + 5][DD];
    int b = blockIdx.x / (DD / SLAB);
    int i0 = (blockIdx.x % (DD / SLAB)) * SLAB;
    int t = threadIdx.x;
    bool c0 = (counters[b] == 0);

    for (int q = t; q < (SLAB + 5) * DD; q += 512) {
        int r = q >> 7, j = q & 127;
        int gi = i0 - 2 + r;
        uint4 p = make_uint4(0, 0, 0, 0), f = make_uint4(0, 0, 0, 0);
        if (gi >= 0 && gi < DD) {
            p = pad0[(b * DD + gi) * DD + j];
            f = fk_pk[(b * DD + gi) * DD + j];
            if (c0 && gi == 127 && j == 127) p.w |= 0x80000000u;  // special voxel (127,127,127)
        }
        padS[r][j] = p; fkS[r][j] = f;
    }
    __syncthreads();

    // union in place over fkS: only (even gi, even j) cells change; no cross-thread hazard
    for (int q = t; q < (SLAB + 4) * DD; q += 512) {
        int r = q >> 7, j = q & 127;
        int gi = i0 - 2 + r;
        if (gi >= 0 && ((gi | j) & 1) == 0) {
            unsigned int q0 = 0, q1 = 0, q2 = 0, q3 = 0;
#pragma unroll
            for (int di2 = 0; di2 < 2; di2++)
#pragma unroll
                for (int dj2 = 0; dj2 < 2; dj2++) {
                    uint4 p = padS[r + di2][j + dj2];
                    uint4 f = fkS[r + di2][j + dj2];
                    q0 |= p.x & ~f.x; q1 |= p.y & ~f.y; q2 |= p.z & ~f.z; q3 |= p.w & ~f.w;
                }
            q0 = (q0 | (q0 >> 1)) & 0x55555555u;
            q1 = (q1 | (q1 >> 1)) & 0x55555555u;
            q2 = (q2 | (q2 >> 1)) & 0x55555555u;
            q3 = (q3 | (q3 >> 1)) & 0x55555555u;
            uint4 u = fkS[r][j];
            u.x |= q0; u.y |= q1; u.z |= q2; u.w |= q3;
            fkS[r][j] = u;
        }
    }
    __syncthreads();

    // j,k-dilate union -> padS (overwrite; pad values no longer needed)
    for (int q = t; q < (SLAB + 4) * DD; q += 512) {
        int r = q >> 7, j = q & 127;
        unsigned int a0 = 0, a1 = 0, a2 = 0, a3 = 0;
#pragma unroll
        for (int dj = -2; dj <= 2; dj++) {
            int jj = j + dj; if (jj < 0 || jj >= DD) continue;
            uint4 x = fkS[r][jj];
            a0 |= x.x; a1 |= x.y; a2 |= x.z; a3 |= x.w;
        }
        unsigned int rr[4]; kdil128(a0, a1, a2, a3, rr);
        padS[r][j] = make_uint4(rr[0], rr[1], rr[2], rr[3]);
    }
    __syncthreads();

    // i-dilate + unpack to floats: rows gi in [i0, i0+SLAB)
    for (int q = t; q < SLAB * DD * 32; q += 512) {
        int c = q & 31;            // float4 chunk within the 128-voxel line
        int line = q >> 5;
        int ioff = line >> 7, j = line & 127;
        int r = ioff + 2;
        int wi = c >> 3, bo = (c & 7) * 4;
        unsigned int w = 0;
#pragma unroll
        for (int di = -2; di <= 2; di++) {
            const unsigned int* pw = (const unsigned int*)&padS[r + di][j];
            w |= pw[wi];
        }
        float4 o;
        o.x = (float)((w >> bo) & 1u);
        o.y = (float)((w >> (bo + 1)) & 1u);
        o.z = (float)((w >> (bo + 2)) & 1u);
        o.w = (float)((w >> (bo + 3)) & 1u);
        outm[((size_t)((b * DD + (i0 + ioff)) * DD + j) * DD >> 2) + c] = o;
    }
}

extern "C" void kernel_launch(void* const* d_in, const int* in_sizes, int n_in,
                              void* d_out, int out_size, void* d_ws, size_t ws_size,
                              hipStream_t stream) {
    (void)in_sizes; (void)n_in; (void)out_size; (void)ws_size;
    const float* sem2d   = (const float*)d_in[0];
    const float* depth   = (const float*)d_in[1];
    const float* occ     = (const float*)d_in[2];
    const int*   kept    = (const int*)d_in[3];
    const float* mapping = (const float*)d_in[4];
    float* out = (float*)d_out;

    float* feats_sm    = (float*)d_ws;                 // B*K*HW
    float* stuffflag   = feats_sm + BB * KK * HW;      // B*HW
    int*   di_arr      = (int*)(stuffflag + BB * HW);  // B*HW
    int*   dmb_arr     = di_arr + BB * HW;             // B*HW
    unsigned int* fk_pk   = (unsigned int*)(dmb_arr + BB * HW); // NVOX/32 each
    unsigned int* kept_pk = fk_pk + NVOX / 32;
    unsigned int* pad0    = kept_pk + NVOX / 32;
    int* counters = (int*)(pad0 + NVOX / 32);

    k1_pixel<<<BB * HW / 256, 256, 0, stream>>>(sem2d, depth, feats_sm, stuffflag, di_arr);
    k23_stuff<<<BB, 256, 0, stream>>>(stuffflag, depth, dmb_arr);

    k45_feat_gather<<<FEAT_BLOCKS + NVOX / 256, 256, 0, stream>>>(
        (const float4*)occ, (const float4*)feats_sm, (const int4*)di_arr, (const int4*)dmb_arr,
        (float4*)out,
        kept, (const float4*)mapping, di_arr, dmb_arr,
        out + (size_t)57600000, fk_pk, kept_pk, counters);

    kA_pad<<<BB * (DD / SLAB), 512, 0, stream>>>((const uint4*)fk_pk, (const uint4*)kept_pk,
                                                 (uint4*)pad0, counters);
    kB_mask<<<BB * (DD / SLAB), 512, 0, stream>>>((const uint4*)pad0, (const uint4*)fk_pk,
                                                  counters, (float4*)(out + (size_t)61794304));
}